// Round 1
// baseline (3314.173 us; speedup 1.0000x reference)
//
#include <hip/hip_runtime.h>
#include <hip/hip_bf16.h>

typedef __hip_bfloat16 bf16;

#define EXP 3
#define BB  4
#define LL  1024
#define DD  768
#define DSN 64
#define DIN 1536
#define DTR 48
#define NDBL 176
#define MM  4096   // B*L rows per expert

struct alignas(16) bf16x8 { bf16 v[8]; };

__device__ __forceinline__ float siluf(float x) { return x / (1.f + __expf(-x)); }
__device__ __forceinline__ float softplusf(float x) {
  return (x > 15.f) ? x : log1pf(__expf(x));
}

// ---------------- LayerNorm row stats: mu, rstd per (e,b,l) ----------------
__launch_bounds__(256)
__global__ void ln_stats_k(const float* __restrict__ pc, float* __restrict__ stats) {
  int row  = blockIdx.x * 4 + (threadIdx.x >> 6);
  int lane = threadIdx.x & 63;
  const float4* x = (const float4*)(pc + (size_t)row * DD);
  float s = 0.f, sq = 0.f;
#pragma unroll
  for (int i = 0; i < 3; i++) {
    float4 v = x[lane + i * 64];
    s  += v.x + v.y + v.z + v.w;
    sq += v.x * v.x + v.y * v.y + v.z * v.z + v.w * v.w;
  }
#pragma unroll
  for (int o = 1; o < 64; o <<= 1) { s += __shfl_xor(s, o); sq += __shfl_xor(sq, o); }
  if (lane == 0) {
    float mu  = s * (1.f / 768.f);
    float var = sq * (1.f / 768.f) - mu * mu;
    stats[row * 2]     = mu;
    stats[row * 2 + 1] = rsqrtf(var + 1e-5f);
  }
}

// ---------------- causal depthwise conv (K=4) + SiLU ----------------
__launch_bounds__(256)
__global__ void conv_silu_k(const bf16* __restrict__ xp, const float* __restrict__ cw,
                            const float* __restrict__ cb, bf16* __restrict__ xs) {
  long i = (long)blockIdx.x * 256 + threadIdx.x;   // < B*L*DI
  int  c  = (int)(i % DIN);
  long rl = i / DIN;                               // b*L + l
  int  l  = (int)(rl & (LL - 1));
  float4 w = *(const float4*)(cw + (size_t)c * 4);
  float wj[4] = {w.x, w.y, w.z, w.w};
  float acc = cb[c];
#pragma unroll
  for (int j = 0; j < 4; j++) {
    int lp = l - 3 + j;
    if (lp >= 0) acc += (float)xp[(rl + j - 3) * DIN + c] * wj[j];
  }
  xs[rl * DIN + c] = (bf16)siluf(acc);
}

// ---------------- generic 128x128 f32 GEMM, templated epilogue ----------------
// MODE 0: A = LN-fused per_ch (f32), out: n<DI -> xp(bf16), else silu -> g(bf16)
// MODE 2: A = dbl f32 (lda=176, K=48), out: softplus(v + b_dt[n]) -> dt(bf16)
// MODE 3: A = y bf16,                 out: d_out = (e==0? base : d_out) + w_e*v
template <int MODE>
__launch_bounds__(256)
__global__ void gemm128_k(const float* __restrict__ Af, const bf16* __restrict__ Ab,
                          const float* __restrict__ Bm, int Kdim, int lda, int ldb,
                          const float* __restrict__ stats,
                          const float* __restrict__ lng, const float* __restrict__ lnb,
                          bf16* __restrict__ out0, bf16* __restrict__ out1,
                          const float* __restrict__ bias,
                          const float* __restrict__ basep, const float* __restrict__ alphap,
                          float* __restrict__ doutp, int eIdx) {
  __shared__ float As[16][132];
  __shared__ float Bs[16][128];
  int t = threadIdx.x, tx = t & 15, ty = t >> 4;
  int n0 = blockIdx.x * 128, r0 = blockIdx.y * 128;
  float acc[8][8] = {};

  for (int k0 = 0; k0 < Kdim; k0 += 16) {
#pragma unroll
    for (int i = 0; i < 8; i++) {                 // A tile 128x16 -> As[k][row]
      int flat = i * 256 + t;
      int row = flat >> 4, kk = flat & 15;
      int gr = r0 + row, k = k0 + kk;
      float v;
      if constexpr (MODE == 0) {
        float x  = Af[(size_t)gr * lda + k];
        float mu = stats[gr * 2], rs = stats[gr * 2 + 1];
        v = (x - mu) * rs * lng[k] + lnb[k];
      } else if constexpr (MODE == 2) {
        v = Af[(size_t)gr * lda + k];
      } else {
        v = (float)Ab[(size_t)gr * lda + k];
      }
      As[kk][row] = v;
    }
#pragma unroll
    for (int i = 0; i < 2; i++) {                 // B tile 16x128
      int f4 = i * 256 + t;
      int kk = f4 >> 5, c4 = (f4 & 31) * 4;
      float4 v = *(const float4*)(Bm + (size_t)(k0 + kk) * ldb + n0 + c4);
      *(float4*)&Bs[kk][c4] = v;
    }
    __syncthreads();
#pragma unroll
    for (int kk = 0; kk < 16; kk++) {
      float a[8], b[8];
      *(float4*)&a[0] = *(const float4*)&As[kk][ty * 8];
      *(float4*)&a[4] = *(const float4*)&As[kk][ty * 8 + 4];
      *(float4*)&b[0] = *(const float4*)&Bs[kk][tx * 8];
      *(float4*)&b[4] = *(const float4*)&Bs[kk][tx * 8 + 4];
#pragma unroll
      for (int ii = 0; ii < 8; ii++)
#pragma unroll
        for (int jj = 0; jj < 8; jj++)
          acc[ii][jj] = fmaf(a[ii], b[jj], acc[ii][jj]);
    }
    __syncthreads();
  }

  int rbase = r0 + ty * 8;
  int nbase = n0 + tx * 8;
  if constexpr (MODE == 0) {
    bool isG = (n0 >= DIN);
    bf16* dst = isG ? out1 : out0;
    int nb = isG ? nbase - DIN : nbase;
#pragma unroll
    for (int ii = 0; ii < 8; ii++) {
      bf16x8 pk;
#pragma unroll
      for (int jj = 0; jj < 8; jj++) {
        float v = acc[ii][jj];
        if (isG) v = siluf(v);
        pk.v[jj] = (bf16)v;
      }
      *(bf16x8*)&dst[(size_t)(rbase + ii) * DIN + nb] = pk;
    }
  } else if constexpr (MODE == 2) {
    float bj[8];
#pragma unroll
    for (int jj = 0; jj < 8; jj++) bj[jj] = bias[nbase + jj];
#pragma unroll
    for (int ii = 0; ii < 8; ii++) {
      bf16x8 pk;
#pragma unroll
      for (int jj = 0; jj < 8; jj++) pk.v[jj] = (bf16)softplusf(acc[ii][jj] + bj[jj]);
      *(bf16x8*)&out0[(size_t)(rbase + ii) * DIN + nbase] = pk;
    }
  } else {
    float a0 = alphap[0], a1 = alphap[1], a2 = alphap[2];
    float mx = fmaxf(a0, fmaxf(a1, a2));
    float e0 = __expf(a0 - mx), e1 = __expf(a1 - mx), e2 = __expf(a2 - mx);
    float wE = ((eIdx == 0) ? e0 : (eIdx == 1) ? e1 : e2) / (e0 + e1 + e2);
#pragma unroll
    for (int ii = 0; ii < 8; ii++) {
      size_t o = (size_t)(rbase + ii) * DD + nbase;
      float4 p0, p1;
      if (eIdx == 0) { p0 = *(const float4*)&basep[o]; p1 = *(const float4*)&basep[o + 4]; }
      else           { p0 = *(const float4*)&doutp[o]; p1 = *(const float4*)&doutp[o + 4]; }
      p0.x = fmaf(wE, acc[ii][0], p0.x); p0.y = fmaf(wE, acc[ii][1], p0.y);
      p0.z = fmaf(wE, acc[ii][2], p0.z); p0.w = fmaf(wE, acc[ii][3], p0.w);
      p1.x = fmaf(wE, acc[ii][4], p1.x); p1.y = fmaf(wE, acc[ii][5], p1.y);
      p1.z = fmaf(wE, acc[ii][6], p1.z); p1.w = fmaf(wE, acc[ii][7], p1.w);
      *(float4*)&doutp[o]     = p0;
      *(float4*)&doutp[o + 4] = p1;
    }
  }
}

// ---------------- 64x64 GEMM for xs @ W_x (N=176, masked) ----------------
__launch_bounds__(256)
__global__ void gemm64_dbl_k(const bf16* __restrict__ xs, const float* __restrict__ Wx,
                             float* __restrict__ dbl) {
  __shared__ float As[16][68];
  __shared__ float Bs[16][68];
  int t = threadIdx.x, tx = t & 15, ty = t >> 4;
  int n0 = blockIdx.x * 64, r0 = blockIdx.y * 64;
  float acc[4][4] = {};
  for (int k0 = 0; k0 < DIN; k0 += 16) {
#pragma unroll
    for (int i = 0; i < 4; i++) {
      int flat = i * 256 + t;
      int row = flat >> 4, kk = flat & 15;
      As[kk][row] = (float)xs[(size_t)(r0 + row) * DIN + k0 + kk];
    }
#pragma unroll
    for (int i = 0; i < 4; i++) {
      int flat = i * 256 + t;
      int kk = flat >> 6, c = flat & 63;
      int n = n0 + c;
      Bs[kk][c] = (n < NDBL) ? Wx[(size_t)(k0 + kk) * NDBL + n] : 0.f;
    }
    __syncthreads();
#pragma unroll
    for (int kk = 0; kk < 16; kk++) {
      float a[4], b[4];
      *(float4*)&a[0] = *(const float4*)&As[kk][ty * 4];
      *(float4*)&b[0] = *(const float4*)&Bs[kk][tx * 4];
#pragma unroll
      for (int ii = 0; ii < 4; ii++)
#pragma unroll
        for (int jj = 0; jj < 4; jj++)
          acc[ii][jj] = fmaf(a[ii], b[jj], acc[ii][jj]);
    }
    __syncthreads();
  }
#pragma unroll
  for (int ii = 0; ii < 4; ii++)
#pragma unroll
    for (int jj = 0; jj < 4; jj++) {
      int n = n0 + tx * 4 + jj;
      if (n < NDBL) dbl[(size_t)(r0 + ty * 4 + ii) * NDBL + n] = acc[ii][jj];
    }
}

// ---------------- selective scan: 4 lanes/channel, 16 states/lane ----------------
__launch_bounds__(256)
__global__ void scan_k(const bf16* __restrict__ dtb, bf16* __restrict__ xsb,
                       const bf16* __restrict__ gb, const float* __restrict__ dbl,
                       const float* __restrict__ A_log, const float* __restrict__ Dsk) {
  int gt = blockIdx.x * 256 + threadIdx.x;
  int sg = gt & 3;
  int cidx = gt >> 2;           // (e*B + b)*DI + d
  int d  = cidx % DIN;
  int eb = cidx / DIN;          // e*B + b
  int e  = eb >> 2;             // B == 4

  float A2[16], h[16];
  const float* Arow = A_log + ((size_t)e * DIN + d) * DSN + sg * 16;
#pragma unroll
  for (int j = 0; j < 16; j++) { A2[j] = -__expf(Arow[j]) * 1.44269504088896f; h[j] = 0.f; }
  float dskip = Dsk[(size_t)e * DIN + d];

  size_t rowbase = (size_t)eb * LL;
  for (int l = 0; l < LL; l++) {
    size_t r   = rowbase + l;
    size_t idx = r * DIN + d;
    float dtv = (float)dtb[idx];
    float u   = (float)xsb[idx];
    float du  = dtv * u;
    const float* dr = dbl + r * NDBL;
    float Bv[16], Cv[16];
    *(float4*)&Bv[0]  = *(const float4*)(dr + DTR + sg * 16);
    *(float4*)&Bv[4]  = *(const float4*)(dr + DTR + sg * 16 + 4);
    *(float4*)&Bv[8]  = *(const float4*)(dr + DTR + sg * 16 + 8);
    *(float4*)&Bv[12] = *(const float4*)(dr + DTR + sg * 16 + 12);
    *(float4*)&Cv[0]  = *(const float4*)(dr + DTR + DSN + sg * 16);
    *(float4*)&Cv[4]  = *(const float4*)(dr + DTR + DSN + sg * 16 + 4);
    *(float4*)&Cv[8]  = *(const float4*)(dr + DTR + DSN + sg * 16 + 8);
    *(float4*)&Cv[12] = *(const float4*)(dr + DTR + DSN + sg * 16 + 12);
    float p = 0.f;
#pragma unroll
    for (int j = 0; j < 16; j++) {
      float dA = exp2f(dtv * A2[j]);
      h[j] = fmaf(dA, h[j], du * Bv[j]);
      p = fmaf(h[j], Cv[j], p);
    }
    p += __shfl_xor(p, 1);
    p += __shfl_xor(p, 2);
    if (sg == 0) {
      float yv = fmaf(u, dskip, p);
      float gv = (float)gb[idx];
      xsb[idx] = (bf16)(yv * gv);   // overwrite xs with gated y (in-wave RAW safe)
    }
  }
}

extern "C" void kernel_launch(void* const* d_in, const int* in_sizes, int n_in,
                              void* d_out, int out_size, void* d_ws, size_t ws_size,
                              hipStream_t stream) {
  const float* base   = (const float*)d_in[0];
  const float* per_ch = (const float*)d_in[1];
  const float* alpha  = (const float*)d_in[2];
  const float* ln_g   = (const float*)d_in[3];
  const float* ln_b   = (const float*)d_in[4];
  const float* W_in   = (const float*)d_in[5];
  const float* conv_w = (const float*)d_in[6];
  const float* conv_b = (const float*)d_in[7];
  const float* W_x    = (const float*)d_in[8];
  const float* W_dt   = (const float*)d_in[9];
  const float* b_dt   = (const float*)d_in[10];
  const float* A_log  = (const float*)d_in[11];
  const float* D_skip = (const float*)d_in[12];
  const float* W_out  = (const float*)d_in[13];
  float* out = (float*)d_out;
  (void)in_sizes; (void)n_in; (void)out_size; (void)ws_size;

  char* ws = (char*)d_ws;
  const size_t BIG = (size_t)EXP * MM * DIN * sizeof(bf16);     // 37,748,736
  bf16*  xsws  = (bf16*)ws;                                     // xs, later gated y
  bf16*  gws   = (bf16*)(ws + BIG);                             // silu(z)
  bf16*  dtws  = (bf16*)(ws + 2 * BIG);                         // xp, later dt
  float* dbl   = (float*)(ws + 3 * BIG);                        // [E*M][176] f32
  float* stats = (float*)(ws + 3 * BIG + (size_t)EXP * MM * NDBL * sizeof(float));

  ln_stats_k<<<EXP * BB * LL / 4, 256, 0, stream>>>(per_ch, stats);

  for (int e = 0; e < EXP; e++) {
    size_t eM = (size_t)e * MM;
    // xz = LN(per_ch) @ W_in -> xp (into dt buffer) + g = silu(z)
    gemm128_k<0><<<dim3(2 * DIN / 128, MM / 128), 256, 0, stream>>>(
        per_ch + eM * DD, nullptr, W_in + (size_t)e * DD * 2 * DIN,
        DD, DD, 2 * DIN, stats + eM * 2, ln_g, ln_b,
        dtws + eM * DIN, gws + eM * DIN, nullptr, nullptr, nullptr, nullptr, 0);
    // causal conv + silu -> xs
    conv_silu_k<<<BB * LL * DIN / 256, 256, 0, stream>>>(
        dtws + eM * DIN, conv_w + (size_t)e * DIN * 4, conv_b + (size_t)e * DIN,
        xsws + eM * DIN);
    // dbl = xs @ W_x (N=176)
    gemm64_dbl_k<<<dim3(3, MM / 64), 256, 0, stream>>>(
        xsws + eM * DIN, W_x + (size_t)e * DIN * NDBL, dbl + eM * NDBL);
    // dt = softplus(dbl[:, :48] @ W_dt + b_dt) -> overwrites xp region
    gemm128_k<2><<<dim3(DIN / 128, MM / 128), 256, 0, stream>>>(
        dbl + eM * NDBL, nullptr, W_dt + (size_t)e * DTR * DIN,
        DTR, NDBL, DIN, nullptr, nullptr, nullptr,
        dtws + eM * DIN, nullptr, b_dt + (size_t)e * DIN, nullptr, nullptr, nullptr, 0);
  }

  // selective scan for all experts; writes gated y over xs buffer
  scan_k<<<EXP * BB * DIN * 4 / 256, 256, 0, stream>>>(
      dtws, xsws, gws, dbl, A_log, D_skip);

  // out = base + sum_e w_e * (y_e @ W_out_e)   (sequential accumulation)
  for (int e = 0; e < EXP; e++) {
    size_t eM = (size_t)e * MM;
    gemm128_k<3><<<dim3(DD / 128, MM / 128), 256, 0, stream>>>(
        nullptr, xsws + eM * DIN, W_out + (size_t)e * DIN * DD,
        DIN, DIN, DD, nullptr, nullptr, nullptr,
        nullptr, nullptr, nullptr, base, alpha, out, e);
  }
}

// Round 2
// 2439.767 us; speedup vs baseline: 1.3584x; 1.3584x over previous
//
#include <hip/hip_runtime.h>
#include <hip/hip_bf16.h>

typedef __hip_bfloat16 bf16;

#define EXP 3
#define BB  4
#define LL  1024
#define DD  768
#define DSN 64
#define DIN 1536
#define DTR 48
#define NDBL 176
#define MM  4096   // B*L rows per expert

struct alignas(16) bf16x8 { bf16 v[8]; };

__device__ __forceinline__ float siluf(float x) { return x / (1.f + __expf(-x)); }
__device__ __forceinline__ float softplusf(float x) {
  return (x > 15.f) ? x : log1pf(__expf(x));
}

// ---------------- LayerNorm row stats: mu, rstd per (e,b,l) ----------------
__launch_bounds__(256)
__global__ void ln_stats_k(const float* __restrict__ pc, float* __restrict__ stats) {
  int row  = blockIdx.x * 4 + (threadIdx.x >> 6);
  int lane = threadIdx.x & 63;
  const float4* x = (const float4*)(pc + (size_t)row * DD);
  float s = 0.f, sq = 0.f;
#pragma unroll
  for (int i = 0; i < 3; i++) {
    float4 v = x[lane + i * 64];
    s  += v.x + v.y + v.z + v.w;
    sq += v.x * v.x + v.y * v.y + v.z * v.z + v.w * v.w;
  }
#pragma unroll
  for (int o = 1; o < 64; o <<= 1) { s += __shfl_xor(s, o); sq += __shfl_xor(sq, o); }
  if (lane == 0) {
    float mu  = s * (1.f / 768.f);
    float var = sq * (1.f / 768.f) - mu * mu;
    stats[row * 2]     = mu;
    stats[row * 2 + 1] = rsqrtf(var + 1e-5f);
  }
}

// ---------------- causal depthwise conv (K=4) + SiLU ----------------
__launch_bounds__(256)
__global__ void conv_silu_k(const bf16* __restrict__ xp, const float* __restrict__ cw,
                            const float* __restrict__ cb, bf16* __restrict__ xs) {
  long i = (long)blockIdx.x * 256 + threadIdx.x;   // < B*L*DI
  int  c  = (int)(i % DIN);
  long rl = i / DIN;                               // b*L + l
  int  l  = (int)(rl & (LL - 1));
  float4 w = *(const float4*)(cw + (size_t)c * 4);
  float wj[4] = {w.x, w.y, w.z, w.w};
  float acc = cb[c];
#pragma unroll
  for (int j = 0; j < 4; j++) {
    int lp = l - 3 + j;
    if (lp >= 0) acc += (float)xp[(rl + j - 3) * DIN + c] * wj[j];
  }
  xs[rl * DIN + c] = (bf16)siluf(acc);
}

// ---------------- generic 128x128 f32 GEMM, templated epilogue ----------------
// MODE 0: A = LN-fused per_ch (f32), out: n<DI -> xp(bf16), else silu -> g(bf16)
// MODE 2: A = dbl f32 (lda=176, K=48), out: softplus(v + b_dt[n]) -> dt(bf16)
// MODE 3: A = y bf16,                 out: d_out = (e==0? base : d_out) + w_e*v
template <int MODE>
__launch_bounds__(256)
__global__ void gemm128_k(const float* __restrict__ Af, const bf16* __restrict__ Ab,
                          const float* __restrict__ Bm, int Kdim, int lda, int ldb,
                          const float* __restrict__ stats,
                          const float* __restrict__ lng, const float* __restrict__ lnb,
                          bf16* __restrict__ out0, bf16* __restrict__ out1,
                          const float* __restrict__ bias,
                          const float* __restrict__ basep, const float* __restrict__ alphap,
                          float* __restrict__ doutp, int eIdx) {
  __shared__ float As[16][132];
  __shared__ float Bs[16][128];
  int t = threadIdx.x, tx = t & 15, ty = t >> 4;
  int n0 = blockIdx.x * 128, r0 = blockIdx.y * 128;
  float acc[8][8] = {};

  for (int k0 = 0; k0 < Kdim; k0 += 16) {
#pragma unroll
    for (int i = 0; i < 8; i++) {                 // A tile 128x16 -> As[k][row]
      int flat = i * 256 + t;
      int row = flat >> 4, kk = flat & 15;
      int gr = r0 + row, k = k0 + kk;
      float v;
      if constexpr (MODE == 0) {
        float x  = Af[(size_t)gr * lda + k];
        float mu = stats[gr * 2], rs = stats[gr * 2 + 1];
        v = (x - mu) * rs * lng[k] + lnb[k];
      } else if constexpr (MODE == 2) {
        v = Af[(size_t)gr * lda + k];
      } else {
        v = (float)Ab[(size_t)gr * lda + k];
      }
      As[kk][row] = v;
    }
#pragma unroll
    for (int i = 0; i < 2; i++) {                 // B tile 16x128
      int f4 = i * 256 + t;
      int kk = f4 >> 5, c4 = (f4 & 31) * 4;
      float4 v = *(const float4*)(Bm + (size_t)(k0 + kk) * ldb + n0 + c4);
      *(float4*)&Bs[kk][c4] = v;
    }
    __syncthreads();
#pragma unroll
    for (int kk = 0; kk < 16; kk++) {
      float a[8], b[8];
      *(float4*)&a[0] = *(const float4*)&As[kk][ty * 8];
      *(float4*)&a[4] = *(const float4*)&As[kk][ty * 8 + 4];
      *(float4*)&b[0] = *(const float4*)&Bs[kk][tx * 8];
      *(float4*)&b[4] = *(const float4*)&Bs[kk][tx * 8 + 4];
#pragma unroll
      for (int ii = 0; ii < 8; ii++)
#pragma unroll
        for (int jj = 0; jj < 8; jj++)
          acc[ii][jj] = fmaf(a[ii], b[jj], acc[ii][jj]);
    }
    __syncthreads();
  }

  int rbase = r0 + ty * 8;
  int nbase = n0 + tx * 8;
  if constexpr (MODE == 0) {
    bool isG = (n0 >= DIN);
    bf16* dst = isG ? out1 : out0;
    int nb = isG ? nbase - DIN : nbase;
#pragma unroll
    for (int ii = 0; ii < 8; ii++) {
      bf16x8 pk;
#pragma unroll
      for (int jj = 0; jj < 8; jj++) {
        float v = acc[ii][jj];
        if (isG) v = siluf(v);
        pk.v[jj] = (bf16)v;
      }
      *(bf16x8*)&dst[(size_t)(rbase + ii) * DIN + nb] = pk;
    }
  } else if constexpr (MODE == 2) {
    float bj[8];
#pragma unroll
    for (int jj = 0; jj < 8; jj++) bj[jj] = bias[nbase + jj];
#pragma unroll
    for (int ii = 0; ii < 8; ii++) {
      bf16x8 pk;
#pragma unroll
      for (int jj = 0; jj < 8; jj++) pk.v[jj] = (bf16)softplusf(acc[ii][jj] + bj[jj]);
      *(bf16x8*)&out0[(size_t)(rbase + ii) * DIN + nbase] = pk;
    }
  } else {
    float a0 = alphap[0], a1 = alphap[1], a2 = alphap[2];
    float mx = fmaxf(a0, fmaxf(a1, a2));
    float e0 = __expf(a0 - mx), e1 = __expf(a1 - mx), e2 = __expf(a2 - mx);
    float wE = ((eIdx == 0) ? e0 : (eIdx == 1) ? e1 : e2) / (e0 + e1 + e2);
#pragma unroll
    for (int ii = 0; ii < 8; ii++) {
      size_t o = (size_t)(rbase + ii) * DD + nbase;
      float4 p0, p1;
      if (eIdx == 0) { p0 = *(const float4*)&basep[o]; p1 = *(const float4*)&basep[o + 4]; }
      else           { p0 = *(const float4*)&doutp[o]; p1 = *(const float4*)&doutp[o + 4]; }
      p0.x = fmaf(wE, acc[ii][0], p0.x); p0.y = fmaf(wE, acc[ii][1], p0.y);
      p0.z = fmaf(wE, acc[ii][2], p0.z); p0.w = fmaf(wE, acc[ii][3], p0.w);
      p1.x = fmaf(wE, acc[ii][4], p1.x); p1.y = fmaf(wE, acc[ii][5], p1.y);
      p1.z = fmaf(wE, acc[ii][6], p1.z); p1.w = fmaf(wE, acc[ii][7], p1.w);
      *(float4*)&doutp[o]     = p0;
      *(float4*)&doutp[o + 4] = p1;
    }
  }
}

// ---------------- 64x64 GEMM for xs @ W_x (N=176, masked) ----------------
__launch_bounds__(256)
__global__ void gemm64_dbl_k(const bf16* __restrict__ xs, const float* __restrict__ Wx,
                             float* __restrict__ dbl) {
  __shared__ float As[16][68];
  __shared__ float Bs[16][68];
  int t = threadIdx.x, tx = t & 15, ty = t >> 4;
  int n0 = blockIdx.x * 64, r0 = blockIdx.y * 64;
  float acc[4][4] = {};
  for (int k0 = 0; k0 < DIN; k0 += 16) {
#pragma unroll
    for (int i = 0; i < 4; i++) {
      int flat = i * 256 + t;
      int row = flat >> 4, kk = flat & 15;
      As[kk][row] = (float)xs[(size_t)(r0 + row) * DIN + k0 + kk];
    }
#pragma unroll
    for (int i = 0; i < 4; i++) {
      int flat = i * 256 + t;
      int kk = flat >> 6, c = flat & 63;
      int n = n0 + c;
      Bs[kk][c] = (n < NDBL) ? Wx[(size_t)(k0 + kk) * NDBL + n] : 0.f;
    }
    __syncthreads();
#pragma unroll
    for (int kk = 0; kk < 16; kk++) {
      float a[4], b[4];
      *(float4*)&a[0] = *(const float4*)&As[kk][ty * 4];
      *(float4*)&b[0] = *(const float4*)&Bs[kk][tx * 4];
#pragma unroll
      for (int ii = 0; ii < 4; ii++)
#pragma unroll
        for (int jj = 0; jj < 4; jj++)
          acc[ii][jj] = fmaf(a[ii], b[jj], acc[ii][jj]);
    }
    __syncthreads();
  }
#pragma unroll
  for (int ii = 0; ii < 4; ii++)
#pragma unroll
    for (int jj = 0; jj < 4; jj++) {
      int n = n0 + tx * 4 + jj;
      if (n < NDBL) dbl[(size_t)(r0 + ty * 4 + ii) * NDBL + n] = acc[ii][jj];
    }
}

// ---------------- selective scan: 16 lanes/channel, 4 states/lane ----------------
// Occupancy fix: 4608 waves (~18/CU) vs old 1152 (~4.5/CU). One-iteration
// manual software pipeline so next step's loads are issued BEFORE this step's
// in-place y store (same-pointer alias otherwise blocks compiler prefetch).
// NOTE: the l+1 prefetch at l=LL-1 reads one row past the logical array; for
// the last (e,b) this lands in the adjacent ws region (still inside d_ws,
// value unused) — safe.
__launch_bounds__(256)
__global__ void scan_k(const bf16* __restrict__ dtb, bf16* __restrict__ xsb,
                       const bf16* __restrict__ gb, const float* __restrict__ dbl,
                       const float* __restrict__ A_log, const float* __restrict__ Dsk) {
  int gt = blockIdx.x * 256 + threadIdx.x;
  int sg = gt & 15;             // state-group lane: states [sg*4, sg*4+4)
  int cidx = gt >> 4;           // (e*B + b)*DI + d
  int d  = cidx % DIN;
  int eb = cidx / DIN;          // e*B + b
  int e  = eb >> 2;             // B == 4

  const float* Arow = A_log + ((size_t)e * DIN + d) * DSN + sg * 4;
  float4 Ar = *(const float4*)Arow;
  float4 A2;
  const float LOG2E = 1.44269504088896f;
  A2.x = -__expf(Ar.x) * LOG2E;
  A2.y = -__expf(Ar.y) * LOG2E;
  A2.z = -__expf(Ar.z) * LOG2E;
  A2.w = -__expf(Ar.w) * LOG2E;
  float4 h = {0.f, 0.f, 0.f, 0.f};
  float dskip = Dsk[(size_t)e * DIN + d];

  size_t idx = (size_t)eb * LL * DIN + d;
  const float* dr = dbl + (size_t)eb * LL * NDBL + DTR + sg * 4;

  // prefetch l = 0
  float dtv = (float)dtb[idx];
  float u   = (float)xsb[idx];
  float gv  = (float)gb[idx];
  float4 Bv = *(const float4*)dr;
  float4 Cv = *(const float4*)(dr + DSN);

  for (int l = 0; l < LL; ++l) {
    // issue next iteration's loads first (hidden under this step's compute)
    size_t idxn = idx + DIN;
    const float* drn = dr + NDBL;
    float dtn = (float)dtb[idxn];
    float un  = (float)xsb[idxn];
    float gn  = (float)gb[idxn];
    float4 Bn = *(const float4*)drn;
    float4 Cn = *(const float4*)(drn + DSN);

    float du = dtv * u;
    float4 dA;
    dA.x = exp2f(dtv * A2.x);
    dA.y = exp2f(dtv * A2.y);
    dA.z = exp2f(dtv * A2.z);
    dA.w = exp2f(dtv * A2.w);
    h.x = fmaf(dA.x, h.x, du * Bv.x);
    h.y = fmaf(dA.y, h.y, du * Bv.y);
    h.z = fmaf(dA.z, h.z, du * Bv.z);
    h.w = fmaf(dA.w, h.w, du * Bv.w);
    float p = h.x * Cv.x + h.y * Cv.y + h.z * Cv.z + h.w * Cv.w;
    p += __shfl_xor(p, 1);
    p += __shfl_xor(p, 2);
    p += __shfl_xor(p, 4);
    p += __shfl_xor(p, 8);
    if (sg == 0) {
      xsb[idx] = (bf16)(fmaf(u, dskip, p) * gv);  // gated y over xs (in-wave RAW safe)
    }
    idx = idxn; dr = drn;
    dtv = dtn; u = un; gv = gn; Bv = Bn; Cv = Cn;
  }
}

extern "C" void kernel_launch(void* const* d_in, const int* in_sizes, int n_in,
                              void* d_out, int out_size, void* d_ws, size_t ws_size,
                              hipStream_t stream) {
  const float* base   = (const float*)d_in[0];
  const float* per_ch = (const float*)d_in[1];
  const float* alpha  = (const float*)d_in[2];
  const float* ln_g   = (const float*)d_in[3];
  const float* ln_b   = (const float*)d_in[4];
  const float* W_in   = (const float*)d_in[5];
  const float* conv_w = (const float*)d_in[6];
  const float* conv_b = (const float*)d_in[7];
  const float* W_x    = (const float*)d_in[8];
  const float* W_dt   = (const float*)d_in[9];
  const float* b_dt   = (const float*)d_in[10];
  const float* A_log  = (const float*)d_in[11];
  const float* D_skip = (const float*)d_in[12];
  const float* W_out  = (const float*)d_in[13];
  float* out = (float*)d_out;
  (void)in_sizes; (void)n_in; (void)out_size; (void)ws_size;

  char* ws = (char*)d_ws;
  const size_t BIG = (size_t)EXP * MM * DIN * sizeof(bf16);     // 37,748,736
  bf16*  xsws  = (bf16*)ws;                                     // xs, later gated y
  bf16*  gws   = (bf16*)(ws + BIG);                             // silu(z)
  bf16*  dtws  = (bf16*)(ws + 2 * BIG);                         // xp, later dt
  float* dbl   = (float*)(ws + 3 * BIG);                        // [E*M][176] f32
  float* stats = (float*)(ws + 3 * BIG + (size_t)EXP * MM * NDBL * sizeof(float));

  ln_stats_k<<<EXP * BB * LL / 4, 256, 0, stream>>>(per_ch, stats);

  for (int e = 0; e < EXP; e++) {
    size_t eM = (size_t)e * MM;
    // xz = LN(per_ch) @ W_in -> xp (into dt buffer) + g = silu(z)
    gemm128_k<0><<<dim3(2 * DIN / 128, MM / 128), 256, 0, stream>>>(
        per_ch + eM * DD, nullptr, W_in + (size_t)e * DD * 2 * DIN,
        DD, DD, 2 * DIN, stats + eM * 2, ln_g, ln_b,
        dtws + eM * DIN, gws + eM * DIN, nullptr, nullptr, nullptr, nullptr, 0);
    // causal conv + silu -> xs
    conv_silu_k<<<BB * LL * DIN / 256, 256, 0, stream>>>(
        dtws + eM * DIN, conv_w + (size_t)e * DIN * 4, conv_b + (size_t)e * DIN,
        xsws + eM * DIN);
    // dbl = xs @ W_x (N=176)
    gemm64_dbl_k<<<dim3(3, MM / 64), 256, 0, stream>>>(
        xsws + eM * DIN, W_x + (size_t)e * DIN * NDBL, dbl + eM * NDBL);
    // dt = softplus(dbl[:, :48] @ W_dt + b_dt) -> overwrites xp region
    gemm128_k<2><<<dim3(DIN / 128, MM / 128), 256, 0, stream>>>(
        dbl + eM * NDBL, nullptr, W_dt + (size_t)e * DTR * DIN,
        DTR, NDBL, DIN, nullptr, nullptr, nullptr,
        dtws + eM * DIN, nullptr, b_dt + (size_t)e * DIN, nullptr, nullptr, nullptr, 0);
  }

  // selective scan for all experts; writes gated y over xs buffer
  scan_k<<<EXP * BB * DIN * 16 / 256, 256, 0, stream>>>(
      dtws, xsws, gws, dbl, A_log, D_skip);

  // out = base + sum_e w_e * (y_e @ W_out_e)   (sequential accumulation)
  for (int e = 0; e < EXP; e++) {
    size_t eM = (size_t)e * MM;
    gemm128_k<3><<<dim3(DD / 128, MM / 128), 256, 0, stream>>>(
        nullptr, xsws + eM * DIN, W_out + (size_t)e * DIN * DD,
        DIN, DIN, DD, nullptr, nullptr, nullptr,
        nullptr, nullptr, nullptr, base, alpha, out, e);
  }
}

// Round 3
// 1112.414 us; speedup vs baseline: 2.9793x; 2.1932x over previous
//
#include <hip/hip_runtime.h>
#include <hip/hip_bf16.h>

typedef __hip_bfloat16 bf16;
typedef unsigned short u16;
typedef __attribute__((ext_vector_type(8))) short s16x8;
typedef __attribute__((ext_vector_type(4))) short s16x4;
typedef __attribute__((ext_vector_type(4))) float f32x4;

#define EXP 3
#define BB  4
#define LL  1024
#define DD  768
#define DSN 64
#define DIN 1536
#define DTR 48
#define MM  4096       // B*L rows per expert
#define DBLLD 256      // dbl cols: 0..47 dt | 48..63 zero | 64..127 B | 128..191 C | 192..255 zero

struct alignas(8)  bf16x4 { bf16 v[4]; };
struct alignas(16) bf16x8 { bf16 v[8]; };

__device__ __forceinline__ float siluf(float x) { return x / (1.f + __expf(-x)); }
__device__ __forceinline__ float softplusf(float x) { return (x > 15.f) ? x : log1pf(__expf(x)); }
__device__ __forceinline__ float bf2f(u16 h) { union { unsigned u; float f; } x; x.u = ((unsigned)h) << 16; return x.f; }

// ---------------- LayerNorm apply + bf16 convert: per_ch -> Abf ----------------
__launch_bounds__(256)
__global__ void ln_apply_k(const float* __restrict__ pc, const float* __restrict__ lng,
                           const float* __restrict__ lnb, bf16* __restrict__ out) {
  int row  = blockIdx.x * 4 + (threadIdx.x >> 6);
  int lane = threadIdx.x & 63;
  const float* x = pc + (size_t)row * DD;
  float4 v[3];
  float s = 0.f, sq = 0.f;
#pragma unroll
  for (int i = 0; i < 3; i++) {
    v[i] = *(const float4*)(x + lane * 4 + i * 256);
    s  += v[i].x + v[i].y + v[i].z + v[i].w;
    sq += v[i].x * v[i].x + v[i].y * v[i].y + v[i].z * v[i].z + v[i].w * v[i].w;
  }
#pragma unroll
  for (int o = 1; o < 64; o <<= 1) { s += __shfl_xor(s, o); sq += __shfl_xor(sq, o); }
  float mu = s * (1.f / 768.f);
  float rs = rsqrtf(sq * (1.f / 768.f) - mu * mu + 1e-5f);
  bf16* op = out + (size_t)row * DD;
#pragma unroll
  for (int i = 0; i < 3; i++) {
    int col = lane * 4 + i * 256;
    float4 g4 = *(const float4*)(lng + col);
    float4 b4 = *(const float4*)(lnb + col);
    bf16x4 pk;
    pk.v[0] = (bf16)((v[i].x - mu) * rs * g4.x + b4.x);
    pk.v[1] = (bf16)((v[i].y - mu) * rs * g4.y + b4.y);
    pk.v[2] = (bf16)((v[i].z - mu) * rs * g4.z + b4.z);
    pk.v[3] = (bf16)((v[i].w - mu) * rs * g4.w + b4.w);
    *(bf16x4*)(op + col) = pk;
  }
}

// ---------------- transpose + f32->bf16 weight conversion ----------------
// out[z][n][k] = in[z][k][map(n)] (or 0 outside). mode 0: plain; mode 1: W_x col
// remap (n<48 -> n, 48..63 -> 0, 64..191 -> n-16, else 0); mode 2: scale by
// softmax(alpha)[z] (W_out pre-weighting).
__launch_bounds__(256)
__global__ void tcvt_k(const float* __restrict__ in, bf16* __restrict__ out,
                       int Ksrc, int ldin, int ldout,
                       size_t sIn, size_t sOut, int mode, const float* __restrict__ alphap) {
  __shared__ float tl[32][33];
  int z = blockIdx.z;
  const float* src = in + (size_t)z * sIn;
  bf16* dst = out + (size_t)z * sOut;
  int n0 = blockIdx.x * 32, k0 = blockIdx.y * 32;
  int tx = threadIdx.x, ty = threadIdx.y;
  int n = n0 + tx;
  int c = n; bool nv = true;
  if (mode == 1) {
    if (n < 48)       c = n;
    else if (n < 64)  nv = false;
    else if (n < 192) c = n - 16;
    else              nv = false;
  }
  float scale = 1.f;
  if (mode == 2) {
    float a0 = alphap[0], a1 = alphap[1], a2 = alphap[2];
    float mx = fmaxf(a0, fmaxf(a1, a2));
    float e0 = __expf(a0 - mx), e1 = __expf(a1 - mx), e2 = __expf(a2 - mx);
    scale = ((z == 0) ? e0 : (z == 1) ? e1 : e2) / (e0 + e1 + e2);
  }
#pragma unroll
  for (int i = 0; i < 32; i += 8) {
    int k = k0 + ty + i;
    float v = (nv && k < Ksrc) ? src[(size_t)k * ldin + c] : 0.f;
    tl[ty + i][tx] = v * scale;
  }
  __syncthreads();
#pragma unroll
  for (int i = 0; i < 32; i += 8) {
    dst[(size_t)(n0 + ty + i) * ldout + (k0 + tx)] = (bf16)tl[tx][ty + i];
  }
}

// ---------------- causal depthwise conv (K=4) + SiLU, 8 channels/thread ----------------
__launch_bounds__(256)
__global__ void conv_silu_k(const bf16* __restrict__ xp, const float* __restrict__ cw,
                            const float* __restrict__ cb, bf16* __restrict__ xs) {
  long i = ((long)blockIdx.x * 256 + threadIdx.x) * 8;   // elem index, 8 channels
  int  c  = (int)(i % DIN);
  long rl = i / DIN;                                     // (e*B + b)*L + l
  int  l  = (int)(rl & (LL - 1));
  int  e  = (int)(rl >> 12);                             // B*L = 4096
  const float* wp  = cw + (size_t)e * DIN * 4 + (size_t)c * 4;
  const float* cbp = cb + (size_t)e * DIN + c;
  float acc[8];
#pragma unroll
  for (int j = 0; j < 8; j++) acc[j] = cbp[j];
#pragma unroll
  for (int tap = 0; tap < 4; tap++) {
    if (l - 3 + tap >= 0) {
      s16x8 xv = *(const s16x8*)(const void*)(xp + (rl + tap - 3) * DIN + c);
#pragma unroll
      for (int j = 0; j < 8; j++)
        acc[j] = fmaf(bf2f((u16)xv[j]), wp[j * 4 + tap], acc[j]);
    }
  }
  bf16x8 pk;
#pragma unroll
  for (int j = 0; j < 8; j++) pk.v[j] = (bf16)siluf(acc[j]);
  *(bf16x8*)(xs + rl * DIN + c) = pk;
}

// ---------------- bf16 MFMA GEMM, 128x128 tile, BK=32, 4 waves x (64x64) ----------------
// C = A[M][K] * Bt[N][K]^T. LDS stores fragments k-permuted so each lane's
// 8-elem mfma operand (k = (l>>4)*4 + (j&3) + 16*(j>>2)) is one ds_read_b128.
// MODE 0: xz GEMM  -> o0=xp bf16 (n<DIN), o1=silu(z) bf16
// MODE 1: dbl GEMM -> o0=dbl bf16 (ld 256, zero-padded cols)
// MODE 2: dt GEMM  -> o0=softplus(acc + bias) bf16
// MODE 3: out GEMM -> atomicAdd into outp (W_out pre-scaled by softmax(alpha))
template<int MODE>
__launch_bounds__(256)
__global__ void mfma_gemm_k(const bf16* __restrict__ A, const bf16* __restrict__ Bt,
                            int Kdim, int lda,
                            size_t sA, size_t sB, size_t sO,
                            bf16* __restrict__ o0, bf16* __restrict__ o1,
                            const float* __restrict__ bias,
                            float* __restrict__ outp) {
  __shared__ short As[128 * 32];
  __shared__ short Bs[128 * 32];
  int z = blockIdx.z;
  A  += (size_t)z * sA;
  Bt += (size_t)z * sB;
  if (o0) o0 += (size_t)z * sO;
  if (o1) o1 += (size_t)z * sO;
  const float* bz = (MODE == 2) ? bias + (size_t)z * DIN : bias;

  int t = threadIdx.x;
  int l = t & 63, w = t >> 6;
  int wr = w >> 1, wc = w & 1;
  int n0 = blockIdx.x * 128, r0 = blockIdx.y * 128;

  int row = t >> 2, c3 = t & 3, col = c3 * 8;
  int plo = ((c3 & 1) ? 16 : 0) + ((c3 & 2) ? 4 : 0);   // k-permuted LDS slot
  int lrow = (l & 15) * 32 + (l >> 4) * 8;

  f32x4 acc[4][4] = {};

  for (int k0 = 0; k0 < Kdim; k0 += 32) {
    s16x8 va0 = *(const s16x8*)(const void*)(A  + (size_t)(r0 + row)      * lda  + k0 + col);
    s16x8 va1 = *(const s16x8*)(const void*)(A  + (size_t)(r0 + row + 64) * lda  + k0 + col);
    s16x8 vb0 = *(const s16x8*)(const void*)(Bt + (size_t)(n0 + row)      * Kdim + k0 + col);
    s16x8 vb1 = *(const s16x8*)(const void*)(Bt + (size_t)(n0 + row + 64) * Kdim + k0 + col);
    __syncthreads();   // previous iteration's ds_reads done
    *(s16x4*)(As + row * 32 + plo)          = __builtin_shufflevector(va0, va0, 0, 1, 2, 3);
    *(s16x4*)(As + row * 32 + plo + 8)      = __builtin_shufflevector(va0, va0, 4, 5, 6, 7);
    *(s16x4*)(As + (row + 64) * 32 + plo)     = __builtin_shufflevector(va1, va1, 0, 1, 2, 3);
    *(s16x4*)(As + (row + 64) * 32 + plo + 8) = __builtin_shufflevector(va1, va1, 4, 5, 6, 7);
    *(s16x4*)(Bs + row * 32 + plo)          = __builtin_shufflevector(vb0, vb0, 0, 1, 2, 3);
    *(s16x4*)(Bs + row * 32 + plo + 8)      = __builtin_shufflevector(vb0, vb0, 4, 5, 6, 7);
    *(s16x4*)(Bs + (row + 64) * 32 + plo)     = __builtin_shufflevector(vb1, vb1, 0, 1, 2, 3);
    *(s16x4*)(Bs + (row + 64) * 32 + plo + 8) = __builtin_shufflevector(vb1, vb1, 4, 5, 6, 7);
    __syncthreads();
    s16x8 af[4], bfv[4];
#pragma unroll
    for (int m = 0; m < 4; m++) af[m]  = *(const s16x8*)(As + (wr * 64 + m * 16) * 32 + lrow);
#pragma unroll
    for (int n = 0; n < 4; n++) bfv[n] = *(const s16x8*)(Bs + (wc * 64 + n * 16) * 32 + lrow);
#pragma unroll
    for (int m = 0; m < 4; m++)
#pragma unroll
      for (int n = 0; n < 4; n++)
        acc[m][n] = __builtin_amdgcn_mfma_f32_16x16x32_bf16(af[m], bfv[n], acc[m][n], 0, 0, 0);
  }

  int rb = r0 + wr * 64 + ((l >> 4) << 2);
  int cb = n0 + wc * 64 + (l & 15);
#pragma unroll
  for (int m = 0; m < 4; m++)
#pragma unroll
    for (int n = 0; n < 4; n++)
#pragma unroll
      for (int r = 0; r < 4; r++) {
        int gr = rb + m * 16 + r;
        int gc = cb + n * 16;
        float v = acc[m][n][r];
        if constexpr (MODE == 0) {
          if (n0 < DIN) o0[(size_t)gr * DIN + gc] = (bf16)v;
          else          o1[(size_t)gr * DIN + (gc - DIN)] = (bf16)siluf(v);
        } else if constexpr (MODE == 1) {
          o0[(size_t)gr * DBLLD + gc] = (bf16)v;
        } else if constexpr (MODE == 2) {
          o0[(size_t)gr * DIN + gc] = (bf16)softplusf(v + bz[gc]);
        } else {
          atomicAdd(&outp[(size_t)gr * DD + gc], v);
        }
      }
}

// ---------------- out = base (init before atomic accumulation) ----------------
__launch_bounds__(256)
__global__ void copy4_k(const float* __restrict__ s, float* __restrict__ d, int n4) {
  int i = blockIdx.x * 256 + threadIdx.x;
  if (i < n4) ((float4*)d)[i] = ((const float4*)s)[i];
}

// ---------------- selective scan: 16 lanes/channel, 4 states/lane ----------------
__launch_bounds__(256)
__global__ void scan_k(const bf16* __restrict__ dtb, bf16* __restrict__ xsb,
                       const bf16* __restrict__ gb, const bf16* __restrict__ dbl,
                       const float* __restrict__ A_log, const float* __restrict__ Dsk) {
  int gt = blockIdx.x * 256 + threadIdx.x;
  int sg = gt & 15;             // states [sg*4, sg*4+4)
  int cidx = gt >> 4;           // (e*B + b)*DI + d
  int d  = cidx % DIN;
  int eb = cidx / DIN;
  int e  = eb >> 2;             // B == 4

  const float* Arow = A_log + ((size_t)e * DIN + d) * DSN + sg * 4;
  float4 Ar = *(const float4*)Arow;
  float4 A2;
  const float LOG2E = 1.44269504088896f;
  A2.x = -__expf(Ar.x) * LOG2E;
  A2.y = -__expf(Ar.y) * LOG2E;
  A2.z = -__expf(Ar.z) * LOG2E;
  A2.w = -__expf(Ar.w) * LOG2E;
  float4 h = {0.f, 0.f, 0.f, 0.f};
  float dskip = Dsk[(size_t)e * DIN + d];

  size_t idx = (size_t)eb * LL * DIN + d;
  const bf16* dr = dbl + (size_t)eb * LL * DBLLD + 64 + sg * 4;   // B; C at +64

  float dtv = (float)dtb[idx];
  float u   = (float)xsb[idx];
  float gv  = (float)gb[idx];
  ushort4 Bu = *(const ushort4*)(const void*)dr;
  ushort4 Cu = *(const ushort4*)(const void*)(dr + 64);

  for (int l = 0; l < LL; ++l) {
    size_t idxn = idx + DIN;
    const bf16* drn = dr + DBLLD;
    float dtn = (float)dtb[idxn];
    float un  = (float)xsb[idxn];
    float gn  = (float)gb[idxn];
    ushort4 Bn = *(const ushort4*)(const void*)drn;
    ushort4 Cn = *(const ushort4*)(const void*)(drn + 64);

    float du = dtv * u;
    float4 Bv = {bf2f(Bu.x), bf2f(Bu.y), bf2f(Bu.z), bf2f(Bu.w)};
    float4 Cv = {bf2f(Cu.x), bf2f(Cu.y), bf2f(Cu.z), bf2f(Cu.w)};
    float4 dA;
    dA.x = exp2f(dtv * A2.x);
    dA.y = exp2f(dtv * A2.y);
    dA.z = exp2f(dtv * A2.z);
    dA.w = exp2f(dtv * A2.w);
    h.x = fmaf(dA.x, h.x, du * Bv.x);
    h.y = fmaf(dA.y, h.y, du * Bv.y);
    h.z = fmaf(dA.z, h.z, du * Bv.z);
    h.w = fmaf(dA.w, h.w, du * Bv.w);
    float p = h.x * Cv.x + h.y * Cv.y + h.z * Cv.z + h.w * Cv.w;
    p += __shfl_xor(p, 1);
    p += __shfl_xor(p, 2);
    p += __shfl_xor(p, 4);
    p += __shfl_xor(p, 8);
    if (sg == 0) {
      xsb[idx] = (bf16)(fmaf(u, dskip, p) * gv);  // gated y over xs
    }
    idx = idxn; dr = drn;
    dtv = dtn; u = un; gv = gn; Bu = Bn; Cu = Cn;
  }
}

extern "C" void kernel_launch(void* const* d_in, const int* in_sizes, int n_in,
                              void* d_out, int out_size, void* d_ws, size_t ws_size,
                              hipStream_t stream) {
  const float* base   = (const float*)d_in[0];
  const float* per_ch = (const float*)d_in[1];
  const float* alpha  = (const float*)d_in[2];
  const float* ln_g   = (const float*)d_in[3];
  const float* ln_b   = (const float*)d_in[4];
  const float* W_in   = (const float*)d_in[5];
  const float* conv_w = (const float*)d_in[6];
  const float* conv_b = (const float*)d_in[7];
  const float* W_x    = (const float*)d_in[8];
  const float* W_dt   = (const float*)d_in[9];
  const float* b_dt   = (const float*)d_in[10];
  const float* A_log  = (const float*)d_in[11];
  const float* D_skip = (const float*)d_in[12];
  const float* W_out  = (const float*)d_in[13];
  float* out = (float*)d_out;
  (void)in_sizes; (void)n_in; (void)out_size; (void)ws_size;

  // Workspace layout (130.4 MB), with lifetime overlays:
  //  R1 [37.75M]: Abf (LN'd per_ch, 18.87M) -> later xs / gated y
  //  R2 [37.75M]: g = silu(z)
  //  R3 [37.75M]: xp -> later dt
  //  R4 [14.16M]: W_inT -> later [dbl bf16 6.29M | W_outT 7.08M]
  //  R5 [ 2.36M]: W_xT ;  R6 [0.59M]: W_dtT
  char* ws = (char*)d_ws;
  const size_t R = (size_t)EXP * MM * DIN * 2;            // 37,748,736
  bf16* Abf   = (bf16*)ws;
  bf16* xsws  = (bf16*)ws;
  bf16* gws   = (bf16*)(ws + R);
  bf16* dtws  = (bf16*)(ws + 2 * R);
  char* R4    = ws + 3 * R;
  bf16* WinT  = (bf16*)R4;
  bf16* dblp  = (bf16*)R4;
  bf16* WoutT = (bf16*)(R4 + (size_t)EXP * MM * DBLLD * 2);   // +6,291,456
  bf16* WxT   = (bf16*)(R4 + 14155776);
  bf16* WdtT  = (bf16*)(R4 + 14155776 + 2359296);

  dim3 blk2(32, 8);

  // prep: LN->bf16, weight transposes (bf16, B^T layout)
  ln_apply_k<<<EXP * BB * LL / 4, 256, 0, stream>>>(per_ch, ln_g, ln_b, Abf);
  tcvt_k<<<dim3(96, 24, EXP), blk2, 0, stream>>>(W_in, WinT, 768, 3072, 768,
        (size_t)768 * 3072, (size_t)3072 * 768, 0, nullptr);
  tcvt_k<<<dim3(8, 48, EXP), blk2, 0, stream>>>(W_x, WxT, 1536, 176, 1536,
        (size_t)1536 * 176, (size_t)256 * 1536, 1, nullptr);
  tcvt_k<<<dim3(48, 2, EXP), blk2, 0, stream>>>(W_dt, WdtT, 48, 1536, 64,
        (size_t)48 * 1536, (size_t)1536 * 64, 0, nullptr);

  // xz = Abf @ W_in -> xp (dtws), silu(z) (gws)
  mfma_gemm_k<0><<<dim3(24, 32, EXP), 256, 0, stream>>>(Abf, WinT, 768, DD,
        (size_t)MM * DD, (size_t)3072 * 768, (size_t)MM * DIN,
        dtws, gws, nullptr, nullptr);

  // W_outT (pre-scaled by softmax(alpha)) — overlays W_inT, safe after MODE0
  tcvt_k<<<dim3(24, 48, EXP), blk2, 0, stream>>>(W_out, WoutT, 1536, 768, 1536,
        (size_t)1536 * 768, (size_t)768 * 1536, 2, alpha);

  // causal conv + silu -> xs (overlays Abf, safe after MODE0)
  conv_silu_k<<<EXP * BB * LL * DIN / 8 / 256, 256, 0, stream>>>(dtws, conv_w, conv_b, xsws);

  // dbl = xs @ W_x (bf16, padded ld 256) — overlays W_inT region
  mfma_gemm_k<1><<<dim3(2, 32, EXP), 256, 0, stream>>>(xsws, WxT, 1536, DIN,
        (size_t)MM * DIN, (size_t)256 * 1536, (size_t)MM * DBLLD,
        dblp, nullptr, nullptr, nullptr);

  // dt = softplus(dbl[:, :64(zero-padded)] @ W_dt + b_dt) -> dtws
  mfma_gemm_k<2><<<dim3(12, 32, EXP), 256, 0, stream>>>(dblp, WdtT, 64, DBLLD,
        (size_t)MM * DBLLD, (size_t)1536 * 64, (size_t)MM * DIN,
        dtws, nullptr, b_dt, nullptr);

  // out = base; selective scan; out += sum_e y_e @ (w_e*W_out_e) via atomics
  copy4_k<<<MM * DD / 4 / 256, 256, 0, stream>>>(base, out, MM * DD / 4);
  scan_k<<<EXP * BB * DIN * 16 / 256, 256, 0, stream>>>(dtws, xsws, gws, dblp, A_log, D_skip);
  mfma_gemm_k<3><<<dim3(6, 32, EXP), 256, 0, stream>>>(xsws, WoutT, 1536, DIN,
        (size_t)MM * DIN, (size_t)768 * 1536, 0,
        nullptr, nullptr, nullptr, out);
}

// Round 5
// 898.363 us; speedup vs baseline: 3.6891x; 1.2383x over previous
//
#include <hip/hip_runtime.h>
#include <hip/hip_bf16.h>

typedef __hip_bfloat16 bf16;
typedef unsigned short u16;
typedef __attribute__((ext_vector_type(8))) short s16x8;
typedef __attribute__((ext_vector_type(4))) short s16x4;
typedef __attribute__((ext_vector_type(4))) float f32x4;

#define EXP 3
#define BB  4
#define LL  1024
#define DD  768
#define DSN 64
#define DIN 1536
#define DTR 48
#define MM  4096       // B*L rows per expert

struct alignas(8)  bf16x4 { bf16 v[4]; };
struct alignas(16) bf16x8 { bf16 v[8]; };

__device__ __forceinline__ float siluf(float x) { return x / (1.f + __expf(-x)); }
__device__ __forceinline__ float softplusf(float x) { return (x > 15.f) ? x : log1pf(__expf(x)); }
__device__ __forceinline__ float bf2f(u16 h) { union { unsigned u; float f; } x; x.u = ((unsigned)h) << 16; return x.f; }

// DPP row-rotate add: x + rotate_right_within_16lane_row(x, n). Rotate-allreduce
// {8,4,2,1} gives the full 16-lane sum in every lane. ctrl must be an ICE ->
// template parameter (0x120 | n = row_ror:n).
template <int CTRL>
__device__ __forceinline__ float ror_add(float x) {
  int y = __builtin_amdgcn_update_dpp(0, __float_as_int(x), CTRL, 0xf, 0xf, true);
  return x + __int_as_float(y);
}

// ---------------- LayerNorm apply + bf16 convert: per_ch -> Abf ----------------
__launch_bounds__(256)
__global__ void ln_apply_k(const float* __restrict__ pc, const float* __restrict__ lng,
                           const float* __restrict__ lnb, bf16* __restrict__ out) {
  int row  = blockIdx.x * 4 + (threadIdx.x >> 6);
  int lane = threadIdx.x & 63;
  const float* x = pc + (size_t)row * DD;
  float4 v[3];
  float s = 0.f, sq = 0.f;
#pragma unroll
  for (int i = 0; i < 3; i++) {
    v[i] = *(const float4*)(x + lane * 4 + i * 256);
    s  += v[i].x + v[i].y + v[i].z + v[i].w;
    sq += v[i].x * v[i].x + v[i].y * v[i].y + v[i].z * v[i].z + v[i].w * v[i].w;
  }
#pragma unroll
  for (int o = 1; o < 64; o <<= 1) { s += __shfl_xor(s, o); sq += __shfl_xor(sq, o); }
  float mu = s * (1.f / 768.f);
  float rs = rsqrtf(sq * (1.f / 768.f) - mu * mu + 1e-5f);
  bf16* op = out + (size_t)row * DD;
#pragma unroll
  for (int i = 0; i < 3; i++) {
    int col = lane * 4 + i * 256;
    float4 g4 = *(const float4*)(lng + col);
    float4 b4 = *(const float4*)(lnb + col);
    bf16x4 pk;
    pk.v[0] = (bf16)((v[i].x - mu) * rs * g4.x + b4.x);
    pk.v[1] = (bf16)((v[i].y - mu) * rs * g4.y + b4.y);
    pk.v[2] = (bf16)((v[i].z - mu) * rs * g4.z + b4.z);
    pk.v[3] = (bf16)((v[i].w - mu) * rs * g4.w + b4.w);
    *(bf16x4*)(op + col) = pk;
  }
}

// ---------------- transpose + f32->bf16 weight conversion ----------------
__launch_bounds__(256)
__global__ void tcvt_k(const float* __restrict__ in, bf16* __restrict__ out,
                       int Ksrc, int ldin, int ldout,
                       size_t sIn, size_t sOut, int mode, const float* __restrict__ alphap) {
  __shared__ float tl[32][33];
  int z = blockIdx.z;
  const float* src = in + (size_t)z * sIn;
  bf16* dst = out + (size_t)z * sOut;
  int n0 = blockIdx.x * 32, k0 = blockIdx.y * 32;
  int tx = threadIdx.x, ty = threadIdx.y;
  int n = n0 + tx;
  int c = n; bool nv = true;
  if (mode == 1) {
    if (n < 48)       c = n;
    else if (n < 64)  nv = false;
    else if (n < 192) c = n - 16;
    else              nv = false;
  }
  float scale = 1.f;
  if (mode == 2) {
    float a0 = alphap[0], a1 = alphap[1], a2 = alphap[2];
    float mx = fmaxf(a0, fmaxf(a1, a2));
    float e0 = __expf(a0 - mx), e1 = __expf(a1 - mx), e2 = __expf(a2 - mx);
    scale = ((z == 0) ? e0 : (z == 1) ? e1 : e2) / (e0 + e1 + e2);
  }
#pragma unroll
  for (int i = 0; i < 32; i += 8) {
    int k = k0 + ty + i;
    float v = (nv && k < Ksrc) ? src[(size_t)k * ldin + c] : 0.f;
    tl[ty + i][tx] = v * scale;
  }
  __syncthreads();
#pragma unroll
  for (int i = 0; i < 32; i += 8) {
    dst[(size_t)(n0 + ty + i) * ldout + (k0 + tx)] = (bf16)tl[tx][ty + i];
  }
}

// ---------------- causal depthwise conv (K=4) + SiLU, 8 channels/thread ----------------
__launch_bounds__(256)
__global__ void conv_silu_k(const bf16* __restrict__ xp, const float* __restrict__ cw,
                            const float* __restrict__ cb, bf16* __restrict__ xs) {
  long i = ((long)blockIdx.x * 256 + threadIdx.x) * 8;   // elem index, 8 channels
  int  c  = (int)(i % DIN);
  long rl = i / DIN;                                     // (e*B + b)*L + l
  int  l  = (int)(rl & (LL - 1));
  int  e  = (int)(rl >> 12);                             // B*L = 4096
  const float* wp  = cw + (size_t)e * DIN * 4 + (size_t)c * 4;
  const float* cbp = cb + (size_t)e * DIN + c;
  float acc[8];
#pragma unroll
  for (int j = 0; j < 8; j++) acc[j] = cbp[j];
#pragma unroll
  for (int tap = 0; tap < 4; tap++) {
    if (l - 3 + tap >= 0) {
      s16x8 xv = *(const s16x8*)(const void*)(xp + (rl + tap - 3) * DIN + c);
#pragma unroll
      for (int j = 0; j < 8; j++)
        acc[j] = fmaf(bf2f((u16)xv[j]), wp[j * 4 + tap], acc[j]);
    }
  }
  bf16x8 pk;
#pragma unroll
  for (int j = 0; j < 8; j++) pk.v[j] = (bf16)siluf(acc[j]);
  *(bf16x8*)(xs + rl * DIN + c) = pk;
}

// ---------------- bf16 MFMA GEMM, 128x128 tile, BK=32, 4 waves x (64x64) ----------------
// MODE 0: xz GEMM  -> o0=xp bf16 (n<DIN), o1=silu(z) bf16
// MODE 1: dbl GEMM -> gc<64 -> dblp bf16 (ld 64); 64..191 -> dblf f32 (ld 128)
// MODE 2: dt GEMM  -> o0=softplus(acc + bias) bf16
// MODE 3: out GEMM -> atomicAdd into outp (W_out pre-scaled by softmax(alpha))
template<int MODE>
__launch_bounds__(256)
__global__ void mfma_gemm_k(const bf16* __restrict__ A, const bf16* __restrict__ Bt,
                            int Kdim, int lda,
                            size_t sA, size_t sB, size_t sO,
                            bf16* __restrict__ o0, bf16* __restrict__ o1,
                            const float* __restrict__ bias,
                            float* __restrict__ outp) {
  __shared__ short As[128 * 32];
  __shared__ short Bs[128 * 32];
  int z = blockIdx.z;
  A  += (size_t)z * sA;
  Bt += (size_t)z * sB;
  if (o0) o0 += (size_t)z * sO;
  if (o1) o1 += (size_t)z * sO;
  if constexpr (MODE == 1) outp += (size_t)z * (size_t)MM * 128;
  const float* bz = (MODE == 2) ? bias + (size_t)z * DIN : bias;

  int t = threadIdx.x;
  int l = t & 63, w = t >> 6;
  int wr = w >> 1, wc = w & 1;
  int n0 = blockIdx.x * 128, r0 = blockIdx.y * 128;

  int row = t >> 2, c3 = t & 3, col = c3 * 8;
  int plo = ((c3 & 1) ? 16 : 0) + ((c3 & 2) ? 4 : 0);   // k-permuted LDS slot
  int lrow = (l & 15) * 32 + (l >> 4) * 8;

  f32x4 acc[4][4] = {};

  for (int k0 = 0; k0 < Kdim; k0 += 32) {
    s16x8 va0 = *(const s16x8*)(const void*)(A  + (size_t)(r0 + row)      * lda  + k0 + col);
    s16x8 va1 = *(const s16x8*)(const void*)(A  + (size_t)(r0 + row + 64) * lda  + k0 + col);
    s16x8 vb0 = *(const s16x8*)(const void*)(Bt + (size_t)(n0 + row)      * Kdim + k0 + col);
    s16x8 vb1 = *(const s16x8*)(const void*)(Bt + (size_t)(n0 + row + 64) * Kdim + k0 + col);
    __syncthreads();   // previous iteration's ds_reads done
    *(s16x4*)(As + row * 32 + plo)          = __builtin_shufflevector(va0, va0, 0, 1, 2, 3);
    *(s16x4*)(As + row * 32 + plo + 8)      = __builtin_shufflevector(va0, va0, 4, 5, 6, 7);
    *(s16x4*)(As + (row + 64) * 32 + plo)     = __builtin_shufflevector(va1, va1, 0, 1, 2, 3);
    *(s16x4*)(As + (row + 64) * 32 + plo + 8) = __builtin_shufflevector(va1, va1, 4, 5, 6, 7);
    *(s16x4*)(Bs + row * 32 + plo)          = __builtin_shufflevector(vb0, vb0, 0, 1, 2, 3);
    *(s16x4*)(Bs + row * 32 + plo + 8)      = __builtin_shufflevector(vb0, vb0, 4, 5, 6, 7);
    *(s16x4*)(Bs + (row + 64) * 32 + plo)     = __builtin_shufflevector(vb1, vb1, 0, 1, 2, 3);
    *(s16x4*)(Bs + (row + 64) * 32 + plo + 8) = __builtin_shufflevector(vb1, vb1, 4, 5, 6, 7);
    __syncthreads();
    s16x8 af[4], bfv[4];
#pragma unroll
    for (int m = 0; m < 4; m++) af[m]  = *(const s16x8*)(As + (wr * 64 + m * 16) * 32 + lrow);
#pragma unroll
    for (int n = 0; n < 4; n++) bfv[n] = *(const s16x8*)(Bs + (wc * 64 + n * 16) * 32 + lrow);
#pragma unroll
    for (int m = 0; m < 4; m++)
#pragma unroll
      for (int n = 0; n < 4; n++)
        acc[m][n] = __builtin_amdgcn_mfma_f32_16x16x32_bf16(af[m], bfv[n], acc[m][n], 0, 0, 0);
  }

  int rb = r0 + wr * 64 + ((l >> 4) << 2);
  int cb = n0 + wc * 64 + (l & 15);
#pragma unroll
  for (int m = 0; m < 4; m++)
#pragma unroll
    for (int n = 0; n < 4; n++)
#pragma unroll
      for (int r = 0; r < 4; r++) {
        int gr = rb + m * 16 + r;
        int gc = cb + n * 16;
        float v = acc[m][n][r];
        if constexpr (MODE == 0) {
          if (n0 < DIN) o0[(size_t)gr * DIN + gc] = (bf16)v;
          else          o1[(size_t)gr * DIN + (gc - DIN)] = (bf16)siluf(v);
        } else if constexpr (MODE == 1) {
          if (gc < 64)       o0[(size_t)gr * 64 + gc] = (bf16)v;
          else if (gc < 192) outp[(size_t)gr * 128 + (gc - 64)] = v;
        } else if constexpr (MODE == 2) {
          o0[(size_t)gr * DIN + gc] = (bf16)softplusf(v + bz[gc]);
        } else {
          atomicAdd(&outp[(size_t)gr * DD + gc], v);
        }
      }
}

// ---------------- out = base (init before atomic accumulation) ----------------
__launch_bounds__(256)
__global__ void copy4_k(const float* __restrict__ s, float* __restrict__ d, int n4) {
  int i = blockIdx.x * 256 + threadIdx.x;
  if (i < n4) ((float4*)d)[i] = ((const float4*)s)[i];
}

// ---------------- selective scan: 16 lanes/channel, 4 states/lane ----------------
// Hand-tuned inner loop: f32 B/C (no converts), DPP rotate-allreduce (no LDS
// ops / address math), raw v_exp_f32, 32-bit offsets, depth-1 load pipeline.
__launch_bounds__(256)
__global__ void scan_k(const bf16* __restrict__ dtb, bf16* __restrict__ xsb,
                       const bf16* __restrict__ gb, const float* __restrict__ dbl,
                       const float* __restrict__ A_log, const float* __restrict__ Dsk) {
  int gt = blockIdx.x * 256 + threadIdx.x;
  int sg = gt & 15;             // states [sg*4, sg*4+4)
  int cidx = gt >> 4;           // (e*B + b)*DI + d
  int d  = cidx % DIN;
  int eb = cidx / DIN;
  int e  = eb >> 2;             // B == 4

  float4 Ar = *(const float4*)(A_log + ((size_t)e * DIN + d) * DSN + sg * 4);
  const float LOG2E = 1.44269504088896f;
  float4 A2;
  A2.x = -__expf(Ar.x) * LOG2E;
  A2.y = -__expf(Ar.y) * LOG2E;
  A2.z = -__expf(Ar.z) * LOG2E;
  A2.w = -__expf(Ar.w) * LOG2E;
  float4 h = {0.f, 0.f, 0.f, 0.f};
  float dskip = Dsk[(size_t)e * DIN + d];

  unsigned idx  = (unsigned)eb * (LL * DIN) + (unsigned)d;   // bf16 elem offset
  unsigned bofs = (unsigned)eb * (LL * 128) + (unsigned)(sg * 4);

  // prefetch l = 0  (final iteration prefetches 1 row past this (e,b) slice;
  // lands in the next ws region, value unused — safe)
  float dtv = (float)dtb[idx];
  float u   = (float)xsb[idx];
  float gv  = (float)gb[idx];
  float4 Bv = *(const float4*)(dbl + bofs);
  float4 Cv = *(const float4*)(dbl + bofs + 64);

#pragma unroll 4
  for (int l = 0; l < LL; ++l) {
    unsigned idxn = idx + DIN;
    unsigned bofn = bofs + 128;
    float dtn = (float)dtb[idxn];
    float un  = (float)xsb[idxn];
    float gn  = (float)gb[idxn];
    float4 Bn = *(const float4*)(dbl + bofn);
    float4 Cn = *(const float4*)(dbl + bofn + 64);

    float du = dtv * u;
    float4 dA;
    dA.x = __builtin_amdgcn_exp2f(dtv * A2.x);
    dA.y = __builtin_amdgcn_exp2f(dtv * A2.y);
    dA.z = __builtin_amdgcn_exp2f(dtv * A2.z);
    dA.w = __builtin_amdgcn_exp2f(dtv * A2.w);
    h.x = fmaf(dA.x, h.x, du * Bv.x);
    h.y = fmaf(dA.y, h.y, du * Bv.y);
    h.z = fmaf(dA.z, h.z, du * Bv.z);
    h.w = fmaf(dA.w, h.w, du * Bv.w);
    float p = fmaf(h.x, Cv.x, fmaf(h.y, Cv.y, fmaf(h.z, Cv.z, h.w * Cv.w)));
    p = ror_add<0x128>(p);   // row_ror:8
    p = ror_add<0x124>(p);   // row_ror:4
    p = ror_add<0x122>(p);   // row_ror:2
    p = ror_add<0x121>(p);   // row_ror:1
    if (sg == 0) {
      xsb[idx] = (bf16)(fmaf(u, dskip, p) * gv);  // gated y over xs
    }
    idx = idxn; bofs = bofn;
    dtv = dtn; u = un; gv = gn; Bv = Bn; Cv = Cn;
  }
}

extern "C" void kernel_launch(void* const* d_in, const int* in_sizes, int n_in,
                              void* d_out, int out_size, void* d_ws, size_t ws_size,
                              hipStream_t stream) {
  const float* base   = (const float*)d_in[0];
  const float* per_ch = (const float*)d_in[1];
  const float* alpha  = (const float*)d_in[2];
  const float* ln_g   = (const float*)d_in[3];
  const float* ln_b   = (const float*)d_in[4];
  const float* W_in   = (const float*)d_in[5];
  const float* conv_w = (const float*)d_in[6];
  const float* conv_b = (const float*)d_in[7];
  const float* W_x    = (const float*)d_in[8];
  const float* W_dt   = (const float*)d_in[9];
  const float* b_dt   = (const float*)d_in[10];
  const float* A_log  = (const float*)d_in[11];
  const float* D_skip = (const float*)d_in[12];
  const float* W_out  = (const float*)d_in[13];
  float* out = (float*)d_out;
  (void)in_sizes; (void)n_in; (void)out_size; (void)ws_size;

  // Workspace layout (131.9 MB), lifetime overlays:
  //  R1 [37.75M]: Abf (18.87M) -> later xs / gated y
  //  R2 [37.75M]: g = silu(z)
  //  R3 [37.75M]: xp -> later dt
  //  R4 [14.16M]: W_inT -> later [WoutT 7.08M | dblf f32 6.29M]
  //  R5 [ 2.36M]: W_xT ;  R6 [0.59M]: W_dtT ;  R7 [1.57M]: dblp bf16 (ld 64)
  char* ws = (char*)d_ws;
  const size_t R = (size_t)EXP * MM * DIN * 2;            // 37,748,736
  bf16* Abf   = (bf16*)ws;
  bf16* xsws  = (bf16*)ws;
  bf16* gws   = (bf16*)(ws + R);
  bf16* dtws  = (bf16*)(ws + 2 * R);
  char* R4    = ws + 3 * R;
  bf16*  WinT  = (bf16*)R4;
  bf16*  WoutT = (bf16*)R4;                               // overlays WinT after MODE0
  float* dblf  = (float*)(R4 + 7077888);                  // E*M*128 f32 = 6.29M
  bf16* WxT   = (bf16*)(ws + 3 * R + 14155776);
  bf16* WdtT  = (bf16*)(ws + 3 * R + 14155776 + 2359296);
  bf16* dblp  = (bf16*)(ws + 3 * R + 14155776 + 2359296 + 589824);

  dim3 blk2(32, 8);

  // prep: LN->bf16, weight transposes (bf16, B^T layout)
  ln_apply_k<<<EXP * BB * LL / 4, 256, 0, stream>>>(per_ch, ln_g, ln_b, Abf);
  tcvt_k<<<dim3(96, 24, EXP), blk2, 0, stream>>>(W_in, WinT, 768, 3072, 768,
        (size_t)768 * 3072, (size_t)3072 * 768, 0, nullptr);
  tcvt_k<<<dim3(8, 48, EXP), blk2, 0, stream>>>(W_x, WxT, 1536, 176, 1536,
        (size_t)1536 * 176, (size_t)256 * 1536, 1, nullptr);
  tcvt_k<<<dim3(48, 2, EXP), blk2, 0, stream>>>(W_dt, WdtT, 48, 1536, 64,
        (size_t)48 * 1536, (size_t)1536 * 64, 0, nullptr);

  // xz = Abf @ W_in -> xp (dtws), silu(z) (gws)
  mfma_gemm_k<0><<<dim3(24, 32, EXP), 256, 0, stream>>>(Abf, WinT, 768, DD,
        (size_t)MM * DD, (size_t)3072 * 768, (size_t)MM * DIN,
        dtws, gws, nullptr, nullptr);

  // W_outT (pre-scaled by softmax(alpha)) — overlays W_inT, safe after MODE0
  tcvt_k<<<dim3(24, 48, EXP), blk2, 0, stream>>>(W_out, WoutT, 1536, 768, 1536,
        (size_t)1536 * 768, (size_t)768 * 1536, 2, alpha);

  // causal conv + silu -> xs (overlays Abf, safe after MODE0)
  conv_silu_k<<<EXP * BB * LL * DIN / 8 / 256, 256, 0, stream>>>(dtws, conv_w, conv_b, xsws);

  // dbl = xs @ W_x: dt cols -> dblp (bf16, ld 64, zero-padded), B|C -> dblf (f32, ld 128)
  mfma_gemm_k<1><<<dim3(2, 32, EXP), 256, 0, stream>>>(xsws, WxT, 1536, DIN,
        (size_t)MM * DIN, (size_t)256 * 1536, (size_t)MM * 64,
        dblp, nullptr, nullptr, dblf);

  // dt = softplus(dblp @ W_dt + b_dt) -> dtws
  mfma_gemm_k<2><<<dim3(12, 32, EXP), 256, 0, stream>>>(dblp, WdtT, 64, 64,
        (size_t)MM * 64, (size_t)1536 * 64, (size_t)MM * DIN,
        dtws, nullptr, b_dt, nullptr);

  // out = base; selective scan; out += sum_e y_e @ (w_e*W_out_e) via atomics
  copy4_k<<<MM * DD / 4 / 256, 256, 0, stream>>>(base, out, MM * DD / 4);
  scan_k<<<EXP * BB * DIN * 16 / 256, 256, 0, stream>>>(dtws, xsws, gws, dblf, A_log, D_skip);
  mfma_gemm_k<3><<<dim3(6, 32, EXP), 256, 0, stream>>>(xsws, WoutT, 1536, DIN,
        (size_t)MM * DIN, (size_t)768 * 1536, 0,
        nullptr, nullptr, nullptr, out);
}